// Round 2
// baseline (194.775 us; speedup 1.0000x reference)
//
#include <hip/hip_runtime.h>
#include <math.h>

// Problem constants (from reference)
#define BB 8
#define SS 64
#define VV 50257
#define PP 200
#define NMASK 1571                      // ceil(VV/32) dedupe mask words
#define NT 1024                         // threads per block
#define ITER 13                         // ceil(max_nb / NT) float4 iters per thread
constexpr float RP   = 1.2f;
constexpr float TINV = 1.0f / 0.6f;     // 1/temperature

// clang native vector type: __builtin_nontemporal_store rejects HIP's
// float4 (a HIP_vector_type class); ext_vector_type(4) is accepted and
// layout-identical (16B).
typedef float f32x4 __attribute__((ext_vector_type(4)));

// One block per (b,s) row; row held register-resident (13 float4/thread).
//
// __launch_bounds__(1024, 4): min 4 waves/EU == exactly 1 workgroup/CU,
// giving the register allocator a 128-VGPR budget. Without the second arg
// the backend's occupancy heuristic (8 waves/EU -> 64-VGPR budget) SPILLED
// buf[13] to scratch (observed VGPR_Count=44 < the 52 regs buf needs),
// which is what capped the r0 version at 2.6 TB/s.
//
// Phases (reordered so row-load latency covers the dedupe phase):
//  1) issue all 13 predicated float4 row loads + head/tail immediately
//  0) prev-token load + 8 scattered batch loads issued next (latency
//     hidden under the row stream); LDS bitmask zero; barrier; atomicOr
//     dedupe; winners compute delta = e^{t_adj} - e^{t_raw}
//  2) e = exp(t) per element, 4-lane accumulate (row already in regs)
//  3) block reduce sum + delta; li = 1/S
//  4) non-temporal write e*li from registers (output is write-once;
//     nt keeps the input L3-resident across iterations)
//  5) barrier (compiler drains vmcnt before s_barrier, ordering the
//     phase-4 stores); winners overwrite their masked entry
__global__ __launch_bounds__(NT, 4) void sch_fused_kernel(
        const float* __restrict__ logits,
        const int*   __restrict__ prev,
        float*       __restrict__ out) {
    __shared__ unsigned mask[NMASK];
    __shared__ float ss[16];
    __shared__ float bc_li;

    const int bs  = blockIdx.x;          // bs = b*SS + s
    const int s   = bs & (SS - 1);
    const int tid = threadIdx.x;
    const float* row  = logits + (size_t)bs * VV;
    float*       orow = out    + (size_t)bs * VV;

    // ---- phase 1: issue all row loads first ---------------------------
    // row element offset = bs*VV ; VV % 4 == 1 -> misalignment = bs % 4
    const int a0   = (4 - (bs & 3)) & 3;               // head elems to 16B align
    const int nb   = (VV - a0) >> 2;                   // float4 body count
    const int tail = VV - a0 - (nb << 2);
    const int tstart = a0 + (nb << 2);

    const f32x4* body = (const f32x4*)(row + a0);
    f32x4 buf[ITER];
    #pragma unroll
    for (int k = 0; k < ITER; ++k) {
        int i = tid + k * NT;
        if (i < nb) buf[k] = body[i];
    }
    // head (<=3) on threads 0..a0-1; tail (<=3) on threads 4..4+tail-1
    float xscal = 0.0f;
    const bool has_head = (tid < a0);
    const bool has_tail = (tid >= 4 && tid < 4 + tail);
    if (has_head) xscal = row[tid];
    if (has_tail) xscal = row[tstart + tid - 4];

    // ---- phase 0: dedupe + sparse correction (latency-hidden) ---------
    int   vtok = -1;
    float lv[BB];
    if (tid < PP) {
        vtok = prev[s * PP + tid];
        // issue the 8 scattered batch loads unconditionally (dupes are
        // L2-hot); consumed only by the winner after the barrier
        #pragma unroll
        for (int b = 0; b < BB; ++b)
            lv[b] = logits[((size_t)(b * SS + s)) * VV + vtok];
    }
    for (int i = tid; i < NMASK; i += NT) mask[i] = 0u;
    __syncthreads();

    float delta  = 0.0f;
    float eadj   = 0.0f;
    bool  winner = false;
    if (tid < PP) {
        unsigned bit = 1u << (vtok & 31);
        unsigned old = atomicOr(&mask[vtok >> 5], bit);
        winner = (old & bit) == 0u;      // one winner per distinct token
        if (winner) {
            bool all_neg = true;
            #pragma unroll
            for (int b = 0; b < BB; ++b) all_neg = all_neg && (lv[b] < 0.0f);
            const float myraw = lv[bs >> 6];           // this block's b
            const float adj   = all_neg ? myraw * RP : myraw / RP;
            eadj  = __expf(adj * TINV);
            delta = eadj - __expf(myraw * TINV);
        }
    }

    // ---- phase 2: exp + accumulate ------------------------------------
    float escal = (has_head || has_tail) ? __expf(xscal * TINV) : 0.0f;
    float accx = 0.f, accy = 0.f, accz = 0.f, accw = 0.f;
    #pragma unroll
    for (int k = 0; k < ITER; ++k) {
        int i = tid + k * NT;
        if (i < nb) {
            f32x4 x = buf[k];
            f32x4 e;
            e.x = __expf(x.x * TINV);
            e.y = __expf(x.y * TINV);
            e.z = __expf(x.z * TINV);
            e.w = __expf(x.w * TINV);
            buf[k] = e;
            accx += e.x; accy += e.y; accz += e.z; accw += e.w;
        }
    }
    float sum = (accx + accy) + (accz + accw) + escal + delta;

    // ---- phase 3: block reduce ----------------------------------------
    #pragma unroll
    for (int off = 1; off < 64; off <<= 1)
        sum += __shfl_xor(sum, off);
    const int wave = tid >> 6, lane = tid & 63;
    if (lane == 0) ss[wave] = sum;
    __syncthreads();
    if (tid == 0) {
        float S0 = ss[0];
        #pragma unroll
        for (int w = 1; w < 16; ++w) S0 += ss[w];
        bc_li = 1.0f / S0;
    }
    __syncthreads();
    const float li = bc_li;

    // ---- phase 4: non-temporal write from registers -------------------
    f32x4* obody = (f32x4*)(orow + a0);
    #pragma unroll
    for (int k = 0; k < ITER; ++k) {
        int i = tid + k * NT;
        if (i < nb) {
            f32x4 e = buf[k];
            f32x4 o;
            o.x = e.x * li; o.y = e.y * li; o.z = e.z * li; o.w = e.w * li;
            __builtin_nontemporal_store(o, &obody[i]);
        }
    }
    if (has_head) __builtin_nontemporal_store(escal * li, &orow[tid]);
    if (has_tail) __builtin_nontemporal_store(escal * li, &orow[tstart + tid - 4]);

    // ---- phase 5: winners overwrite masked entries --------------------
    __syncthreads();   // orders phase-4 stores before the overwrite
    if (winner) orow[vtok] = eadj * li;
}

extern "C" void kernel_launch(void* const* d_in, const int* in_sizes, int n_in,
                              void* d_out, int out_size, void* d_ws, size_t ws_size,
                              hipStream_t stream) {
    const float* logits = (const float*)d_in[0];
    const int*   prev   = (const int*)d_in[1];
    float* out = (float*)d_out;

    sch_fused_kernel<<<BB * SS, NT, 0, stream>>>(logits, prev, out);
}